// Round 5
// baseline (600.655 us; speedup 1.0000x reference)
//
#include <hip/hip_runtime.h>
#include <math.h>

// ---------------------------------------------------------------------------
// HDRNet, N=4, low 256x256, full 1024x1024. 6-launch pipeline:
//   k01: conv0+conv1 fused via LDS halo tile (64 blocks)
//   k23: conv2+conv3 fused via LDS halo tile (64 blocks)
//   k5 : l0 + g1 + splat-means (6208 blocks)
//   k6 : l1 + g2 + x1-means (5248 blocks)
//   kfc: FC chain (redundant per block, LDS) + fuse_grid (384 blocks)
//   hdr: fused guide/slice/YUV output (R2 form — VGPR 128 occupancy cliff!)
// Workspace floats: t1 262144 | splat 65536 | l0o 65536 | local 65536 |
// x1 32768 | x2 16384 | avec 1792 | grid (4,8,16,16,12) 98304
// ---------------------------------------------------------------------------

__device__ __forceinline__ float tanh_fast(float x) {
    float e = __expf(2.0f * x);
    return 1.0f - 2.0f / (e + 1.0f);
}

// ---- k01: conv0 (3->8, s2) + conv1 (8->16, s2) fused.
// Block = (n, 16x16 t1 tile). t0 halo 33x33x8 in LDS.
__global__ __launch_bounds__(256) void k01_fused(
    const float* __restrict__ low,
    const float* __restrict__ w0, const float* __restrict__ b0,
    const float* __restrict__ w1, const float* __restrict__ b1,
    float* __restrict__ t1out)
{
    __shared__ float t0L[8 * 33 * 33];           // 34848 B
    int blk = blockIdx.x;
    int n = blk >> 4; int tile = blk & 15;
    int R0 = (tile >> 2) * 16, C0 = (tile & 3) * 16;   // t1 tile origin
    const float* lowN = low + (size_t)n * 3 * 65536;

    // phase A: t0 window (t0 coords gy0=2*R0-1 .. +32), zero outside [0,128)
    for (int t = threadIdx.x; t < 8712; t += 256) {
        int ch = t / 1089; int rem = t % 1089;
        int r = rem / 33; int cc = rem % 33;
        int gy = 2 * R0 - 1 + r, gx = 2 * C0 - 1 + cc;
        float val = 0.0f;
        if ((unsigned)gy < 128u && (unsigned)gx < 128u) {
            float acc = b0[ch];
            const float* wp = w0 + ch * 27;
            int hi0 = 2 * gy - 1, wi0 = 2 * gx - 1;
            #pragma unroll
            for (int ci = 0; ci < 3; ++ci) {
                const float* ip = lowN + (size_t)ci * 65536;
                #pragma unroll
                for (int kh = 0; kh < 3; ++kh) {
                    int hi = hi0 + kh;
                    if ((unsigned)hi >= 256u) continue;
                    #pragma unroll
                    for (int kw = 0; kw < 3; ++kw) {
                        int wi = wi0 + kw;
                        if ((unsigned)wi >= 256u) continue;
                        acc = fmaf(wp[ci * 9 + kh * 3 + kw], ip[hi * 256 + wi], acc);
                    }
                }
            }
            val = fmaxf(acc, 0.0f);
        }
        t0L[t] = val;
    }
    __syncthreads();

    // phase B: t1 tile; thread = c*16 + i, loops j (16 cols)
    int c = threadIdx.x >> 4, i = threadIdx.x & 15;
    float acc[16];
    float bc = b1[c];
    #pragma unroll
    for (int j = 0; j < 16; ++j) acc[j] = bc;
    const float* wb = w1 + c * 72;
    #pragma unroll
    for (int ch = 0; ch < 8; ++ch) {
        #pragma unroll
        for (int kh = 0; kh < 3; ++kh) {
            const float* rowp = &t0L[ch * 1089 + (2 * i + kh) * 33];
            float q0 = wb[ch * 9 + kh * 3 + 0];
            float q1 = wb[ch * 9 + kh * 3 + 1];
            float q2 = wb[ch * 9 + kh * 3 + 2];
            #pragma unroll
            for (int j = 0; j < 16; ++j) {
                acc[j] = fmaf(q0, rowp[2 * j], acc[j]);
                acc[j] = fmaf(q1, rowp[2 * j + 1], acc[j]);
                acc[j] = fmaf(q2, rowp[2 * j + 2], acc[j]);
            }
        }
    }
    float* op = t1out + (((size_t)(n * 16 + c)) * 64 + (R0 + i)) * 64 + C0;
    #pragma unroll
    for (int j = 0; j < 16; ++j) op[j] = fmaxf(acc[j], 0.0f);
}

// ---- k23: conv2 (16->32, s2) + conv3 (32->64, s2) fused.
// Block = (n, 4x4 splat tile). t2 halo 9x9x32 in LDS.
__global__ __launch_bounds__(256) void k23_fused(
    const float* __restrict__ t1, const float* __restrict__ w2,
    const float* __restrict__ b2, const float* __restrict__ w3,
    const float* __restrict__ b3, float* __restrict__ splat)
{
    __shared__ float t2L[32 * 81];               // 10368 B
    int blk = blockIdx.x;
    int n = blk >> 4; int tile = blk & 15;
    int R0 = (tile >> 2) * 4, C0 = (tile & 3) * 4;     // splat tile origin
    const float* t1N = t1 + (size_t)n * 16 * 4096;

    for (int t = threadIdx.x; t < 2592; t += 256) {
        int ch = t / 81; int rem = t % 81;
        int r = rem / 9; int cc = rem % 9;
        int gy = 2 * R0 - 1 + r, gx = 2 * C0 - 1 + cc;
        float val = 0.0f;
        if ((unsigned)gy < 32u && (unsigned)gx < 32u) {
            float acc = b2[ch];
            const float* wp = w2 + ch * 144;
            int hi0 = 2 * gy - 1, wi0 = 2 * gx - 1;
            #pragma unroll
            for (int ci = 0; ci < 16; ++ci) {
                const float* ip = t1N + (size_t)ci * 4096;
                #pragma unroll
                for (int kh = 0; kh < 3; ++kh) {
                    int hi = hi0 + kh;
                    if ((unsigned)hi >= 64u) continue;
                    #pragma unroll
                    for (int kw = 0; kw < 3; ++kw) {
                        int wi = wi0 + kw;
                        if ((unsigned)wi >= 64u) continue;
                        acc = fmaf(wp[ci * 9 + kh * 3 + kw], ip[hi * 64 + wi], acc);
                    }
                }
            }
            val = fmaxf(acc, 0.0f);
        }
        t2L[t] = val;
    }
    __syncthreads();

    // splat tile: thread = c*4 + i, loops j (4 cols)
    int c = threadIdx.x >> 2, i = threadIdx.x & 3;
    float acc[4];
    float bc = b3[c];
    #pragma unroll
    for (int j = 0; j < 4; ++j) acc[j] = bc;
    const float* wb = w3 + c * 288;
    #pragma unroll
    for (int ch = 0; ch < 32; ++ch) {
        #pragma unroll
        for (int kh = 0; kh < 3; ++kh) {
            const float* rowp = &t2L[ch * 81 + (2 * i + kh) * 9];
            float q0 = wb[ch * 9 + kh * 3 + 0];
            float q1 = wb[ch * 9 + kh * 3 + 1];
            float q2 = wb[ch * 9 + kh * 3 + 2];
            #pragma unroll
            for (int j = 0; j < 4; ++j) {
                acc[j] = fmaf(q0, rowp[2 * j], acc[j]);
                acc[j] = fmaf(q1, rowp[2 * j + 1], acc[j]);
                acc[j] = fmaf(q2, rowp[2 * j + 2], acc[j]);
            }
        }
    }
    float* op = splat + (((size_t)(n * 64 + c)) * 16 + (R0 + i)) * 16 + C0;
    #pragma unroll
    for (int j = 0; j < 4; ++j) op[j] = fmaxf(acc[j], 0.0f);
}

// ---- PARTS-way input-channel-split 3x3 conv (from R4, validated)
template<int CIN, int PARTS, int STRIDE, bool RELU, bool HASB,
         int COUT, int HIN, int WIN, int HOUT, int WOUT>
__device__ __forceinline__ void conv_p_dev(
    const float* __restrict__ in, const float* __restrict__ w,
    const float* __restrict__ b, float* __restrict__ out,
    int tb, float* red)
{
    constexpr int CPT = CIN / PARTS;
    constexpr int OPB = 256 / PARTS;
    int part = threadIdx.x / OPB;
    int oidx = threadIdx.x % OPB;
    int o = tb * OPB + oidx;
    int wo = o % WOUT; int t = o / WOUT;
    int ho = t % HOUT; t /= HOUT;
    int co = t % COUT; int n = t / COUT;
    int hi0 = ho * STRIDE - 1, wi0 = wo * STRIDE - 1;
    const float* wp = w + ((size_t)co * CIN + part * CPT) * 9;
    const float* ip = in + ((size_t)n * CIN + part * CPT) * HIN * WIN;
    float acc = 0.0f;
    #pragma unroll
    for (int ci = 0; ci < CPT; ++ci) {
        const float* ic = ip + (size_t)ci * HIN * WIN;
        const float* wc = wp + ci * 9;
        #pragma unroll
        for (int kh = 0; kh < 3; ++kh) {
            int hi = hi0 + kh;
            if ((unsigned)hi >= (unsigned)HIN) continue;
            const float* row = ic + hi * WIN;
            #pragma unroll
            for (int kw = 0; kw < 3; ++kw) {
                int wi = wi0 + kw;
                if ((unsigned)wi >= (unsigned)WIN) continue;
                acc = fmaf(wc[kh * 3 + kw], row[wi], acc);
            }
        }
    }
    red[threadIdx.x] = acc;
    __syncthreads();
    if (part == 0) {
        float s = acc;
        #pragma unroll
        for (int p = 1; p < PARTS; ++p) s += red[p * OPB + oidx];
        if (HASB) s += b[co];
        if (RELU) s = fmaxf(s, 0.0f);
        out[o] = s;
    }
}

// k5: l0 (4096 tbs) + g1 (2048 tbs) + splat-means (64 blocks)
__global__ __launch_bounds__(256) void k5_l0_g1_means(
    const float* __restrict__ splat,
    const float* __restrict__ wl0, const float* __restrict__ bl0, float* __restrict__ l0o,
    const float* __restrict__ wg1, const float* __restrict__ bg1, float* __restrict__ x1,
    float* __restrict__ avec)
{
    __shared__ float red[256];
    int bid = blockIdx.x;
    if (bid < 4096) {
        conv_p_dev<64, 16, 1, true, true, 64, 16, 16, 16, 16>(splat, wl0, bl0, l0o, bid, red);
    } else if (bid < 6144) {
        conv_p_dev<64, 16, 2, true, true, 128, 16, 16, 8, 8>(splat, wg1, bg1, x1, bid - 4096, red);
    } else {
        int wid = (bid - 6144) * 4 + (threadIdx.x >> 6);   // 0..255
        int lane = threadIdx.x & 63;
        int n = wid >> 6, c = wid & 63;
        const float* p = splat + ((size_t)(n * 64 + c)) * 256;
        float s = p[lane] + p[lane + 64] + p[lane + 128] + p[lane + 192];
        #pragma unroll
        for (int off = 32; off; off >>= 1) s += __shfl_down(s, off, 64);
        if (lane == 0) avec[n * 448 + c] = s * (1.0f / 256.0f);
    }
}

// k6: l1 (4096 tbs) + g2 (1024 tbs) + x1-means (128 blocks)
__global__ __launch_bounds__(256) void k6_l1_g2_means(
    const float* __restrict__ l0o, const float* __restrict__ wl1, float* __restrict__ localb,
    const float* __restrict__ x1, const float* __restrict__ wg2,
    const float* __restrict__ bg2, float* __restrict__ x2,
    float* __restrict__ avec)
{
    __shared__ float red[256];
    int bid = blockIdx.x;
    if (bid < 4096) {
        conv_p_dev<64, 16, 1, false, false, 64, 16, 16, 16, 16>(l0o, wl1, nullptr, localb, bid, red);
    } else if (bid < 5120) {
        conv_p_dev<128, 16, 2, true, true, 256, 8, 8, 4, 4>(x1, wg2, bg2, x2, bid - 4096, red);
    } else {
        int wid = (bid - 5120) * 4 + (threadIdx.x >> 6);   // 0..511
        int lane = threadIdx.x & 63;
        int n = wid >> 7, c = wid & 127;
        const float* p = x1 + ((size_t)(n * 128 + c)) * 64;
        float s = p[lane];
        #pragma unroll
        for (int off = 32; off; off >>= 1) s += __shfl_down(s, off, 64);
        if (lane == 0) avec[n * 448 + 64 + c] = s * (1.0f / 64.0f);
    }
}

// kfc: per-block redundant FC chain (448->256->128->64 in LDS) + fuse_grid.
// Block b: n = b/96, k = b%96; thread = grid cell p. Writes channel-innermost.
__global__ __launch_bounds__(256) void kfc_fuse(
    const float* __restrict__ avec, const float* __restrict__ x2,
    const float* __restrict__ wf1, const float* __restrict__ bf1,
    const float* __restrict__ wf2, const float* __restrict__ bf2,
    const float* __restrict__ wf3, const float* __restrict__ bf3,
    const float* __restrict__ local,
    const float* __restrict__ wlin, const float* __restrict__ blin,
    float* __restrict__ grid)
{
    __shared__ float a[448];
    __shared__ float h1[256];
    __shared__ float h2[128];
    __shared__ float gl[64];
    int n = blockIdx.x / 96; int k = blockIdx.x % 96; int t = threadIdx.x;
    if (t < 192) a[t] = avec[n * 448 + t];
    {
        const float* p = x2 + ((size_t)(n * 256 + t)) * 16;
        float s = 0.0f;
        #pragma unroll
        for (int i = 0; i < 16; ++i) s += p[i];
        a[192 + t] = s * (1.0f / 16.0f);
    }
    __syncthreads();
    {
        float a0 = 0, a1 = 0, a2 = 0, a3 = 0;
        const float* wp = wf1 + (size_t)t * 448;
        for (int i = 0; i < 448; i += 4) {
            a0 = fmaf(wp[i], a[i], a0); a1 = fmaf(wp[i + 1], a[i + 1], a1);
            a2 = fmaf(wp[i + 2], a[i + 2], a2); a3 = fmaf(wp[i + 3], a[i + 3], a3);
        }
        h1[t] = fmaxf(a0 + a1 + a2 + a3 + bf1[t], 0.0f);
    }
    __syncthreads();
    if (t < 128) {
        float a0 = 0, a1 = 0, a2 = 0, a3 = 0;
        const float* wp = wf2 + (size_t)t * 256;
        for (int i = 0; i < 256; i += 4) {
            a0 = fmaf(wp[i], h1[i], a0); a1 = fmaf(wp[i + 1], h1[i + 1], a1);
            a2 = fmaf(wp[i + 2], h1[i + 2], a2); a3 = fmaf(wp[i + 3], h1[i + 3], a3);
        }
        h2[t] = fmaxf(a0 + a1 + a2 + a3 + bf2[t], 0.0f);
    }
    __syncthreads();
    if (t < 64) {
        float a0 = 0, a1 = 0, a2 = 0, a3 = 0;
        const float* wp = wf3 + (size_t)t * 128;
        for (int i = 0; i < 128; i += 4) {
            a0 = fmaf(wp[i], h2[i], a0); a1 = fmaf(wp[i + 1], h2[i + 1], a1);
            a2 = fmaf(wp[i + 2], h2[i + 2], a2); a3 = fmaf(wp[i + 3], h2[i + 3], a3);
        }
        gl[t] = fmaxf(a0 + a1 + a2 + a3 + bf3[t], 0.0f);
    }
    __syncthreads();
    float acc = blin[k];
    const float* wp = wlin + k * 64;
    const float* lo = local + (size_t)n * 64 * 256 + t;
    #pragma unroll 8
    for (int c = 0; c < 64; ++c)
        acc = fmaf(wp[c], fmaxf(gl[c] + lo[c * 256], 0.0f), acc);
    int ch = k >> 3; int z = k & 7;
    grid[(((size_t)(n * 8 + z)) * 256 + t) * 12 + ch] = acc;
}

// ---- hdr: R2's hdr_out_v2 verbatim (87us, VGPR 128 — occupancy cliff, do
// not add registers). 4 px per thread.
__global__ __launch_bounds__(256, 4) void hdr_out_v2(
    const float* __restrict__ full, const float* __restrict__ low,
    const float* __restrict__ grid,
    const float* __restrict__ wgd1, const float* __restrict__ bgd1,
    const float* __restrict__ wgd2, const float* __restrict__ bgd2,
    const float* __restrict__ wau1, const float* __restrict__ bau1,
    const float* __restrict__ wau2, const float* __restrict__ bau2,
    const float* __restrict__ wav1, const float* __restrict__ bav1,
    const float* __restrict__ wav2, const float* __restrict__ bav2,
    float* __restrict__ out)
{
    int tid = blockIdx.x * 256 + threadIdx.x;
    int x0 = (tid & 255) << 2;
    int y = (tid >> 8) & 1023;
    int n = tid >> 18;
    const float* fp = full + ((size_t)n << 20);

    float v[3][6];
    #pragma unroll
    for (int r = 0; r < 3; ++r) {
        int yy = y + r - 1;
        bool okr = (unsigned)yy < 1024u;
        const float* row = fp + (size_t)yy * 1024;
        if (okr) {
            float4 m = *(const float4*)(row + x0);
            v[r][1] = m.x; v[r][2] = m.y; v[r][3] = m.z; v[r][4] = m.w;
            v[r][0] = (x0 > 0) ? row[x0 - 1] : 0.0f;
            v[r][5] = (x0 < 1020) ? row[x0 + 4] : 0.0f;
        } else {
            #pragma unroll
            for (int j = 0; j < 6; ++j) v[r][j] = 0.0f;
        }
    }

    float gacc[4];
    float bb = bgd2[0];
    #pragma unroll
    for (int px = 0; px < 4; ++px) gacc[px] = bb;
    #pragma unroll
    for (int k = 0; k < 16; ++k) {
        const float* wk = wgd1 + k * 9;
        float q0 = wk[0], q1 = wk[1], q2 = wk[2];
        float q3 = wk[3], q4 = wk[4], q5 = wk[5];
        float q6 = wk[6], q7 = wk[7], q8 = wk[8];
        float bk = bgd1[k], wo = wgd2[k];
        #pragma unroll
        for (int px = 0; px < 4; ++px) {
            float h = bk;
            h = fmaf(q0, v[0][px], h); h = fmaf(q1, v[0][px + 1], h); h = fmaf(q2, v[0][px + 2], h);
            h = fmaf(q3, v[1][px], h); h = fmaf(q4, v[1][px + 1], h); h = fmaf(q5, v[1][px + 2], h);
            h = fmaf(q6, v[2][px], h); h = fmaf(q7, v[2][px + 1], h); h = fmaf(q8, v[2][px + 2], h);
            gacc[px] = fmaf(wo, fmaxf(h, 0.0f), gacc[px]);
        }
    }

    const float* gbase = grid + (size_t)n * 24576;
    float Yo[4], Uo[4], Vo[4];

    #pragma unroll
    for (int px = 0; px < 4; ++px) {
        int x = x0 + px;
        float g = tanh_fast(gacc[px]);

        float gxc = (x * (32.0f / 1023.0f) - 1.0f) * 0.5f;
        float gyc = (y * (32.0f / 1023.0f) - 1.0f) * 0.5f;
        float gzc = 4.0f * g + 3.5f;
        float x0f = floorf(gxc), y0f = floorf(gyc), z0f = floorf(gzc);
        float fx = gxc - x0f, fy = gyc - y0f, fz = gzc - z0f;
        int ix = (int)x0f, iy = (int)y0f, iz = (int)z0f;

        float wx0 = (ix >= 0 && ix < 16) ? (1.0f - fx) : 0.0f;
        float wx1 = (ix + 1 < 16) ? fx : 0.0f;
        float wy0 = (iy >= 0 && iy < 16) ? (1.0f - fy) : 0.0f;
        float wy1 = (iy + 1 < 16) ? fy : 0.0f;
        float wz0 = (iz >= 0 && iz < 8) ? (1.0f - fz) : 0.0f;
        float wz1 = (iz + 1 >= 0 && iz + 1 < 8) ? fz : 0.0f;
        int xi0 = min(max(ix, 0), 15), xi1 = min(ix + 1, 15);
        int yi0 = min(max(iy, 0), 15), yi1 = min(iy + 1, 15);
        int zi0 = min(max(iz, 0), 7),  zi1 = min(max(iz + 1, 0), 7);

        float w00 = wy0 * wx0, w01 = wy0 * wx1, w10 = wy1 * wx0, w11 = wy1 * wx1;
        int o00 = yi0 * 16 + xi0, o01 = yi0 * 16 + xi1;
        int o10 = yi1 * 16 + xi0, o11 = yi1 * 16 + xi1;
        int z0b = zi0 * 256, z1b = zi1 * 256;

        float acc[12];
        #pragma unroll
        for (int i = 0; i < 12; ++i) acc[i] = 0.0f;

        #define CORNER(OFF, WK) { \
            const float4* q = (const float4*)(gbase + (size_t)(OFF) * 12); \
            float wk_ = (WK); \
            float4 A = q[0], B = q[1], C = q[2]; \
            acc[0] = fmaf(wk_, A.x, acc[0]); acc[1] = fmaf(wk_, A.y, acc[1]); \
            acc[2] = fmaf(wk_, A.z, acc[2]); acc[3] = fmaf(wk_, A.w, acc[3]); \
            acc[4] = fmaf(wk_, B.x, acc[4]); acc[5] = fmaf(wk_, B.y, acc[5]); \
            acc[6] = fmaf(wk_, B.z, acc[6]); acc[7] = fmaf(wk_, B.w, acc[7]); \
            acc[8] = fmaf(wk_, C.x, acc[8]); acc[9] = fmaf(wk_, C.y, acc[9]); \
            acc[10] = fmaf(wk_, C.z, acc[10]); acc[11] = fmaf(wk_, C.w, acc[11]); }

        CORNER(z0b + o00, wz0 * w00)
        CORNER(z0b + o01, wz0 * w01)
        CORNER(z0b + o10, wz0 * w10)
        CORNER(z0b + o11, wz0 * w11)
        CORNER(z1b + o00, wz1 * w00)
        CORNER(z1b + o01, wz1 * w01)
        CORNER(z1b + o10, wz1 * w10)
        CORNER(z1b + o11, wz1 * w11)
        #undef CORNER

        float p = v[1][px + 1];
        float Yv = fmaf(p, acc[3],  acc[0] + acc[1] + acc[2]);
        float U0 = fmaf(p, acc[7],  acc[4] + acc[5] + acc[6]);
        float V0 = fmaf(p, acc[11], acc[8] + acc[9] + acc[10]);

        float uacc = bau2[0];
        #pragma unroll
        for (int k = 0; k < 16; ++k)
            uacc = fmaf(wau2[k], fmaxf(fmaf(wau1[k], U0, bau1[k]), 0.0f), uacc);
        float vacc = bav2[0];
        #pragma unroll
        for (int k = 0; k < 16; ++k)
            vacc = fmaf(wav2[k], fmaxf(fmaf(wav1[k], V0, bav1[k]), 0.0f), vacc);

        float sx = (x + 0.5f) * 0.25f - 0.5f;
        float sy = (y + 0.5f) * 0.25f - 0.5f;
        float sxf = floorf(sx), syf = floorf(sy);
        float fxl = sx - sxf, fyl = sy - syf;
        int jx0 = max((int)sxf, 0), jx1 = min((int)sxf + 1, 255);
        int jy0 = max((int)syf, 0), jy1 = min((int)syf + 1, 255);
        const float* lr1 = low + ((size_t)(n * 3 + 1)) * 65536;
        const float* lr2 = low + ((size_t)(n * 3 + 2)) * 65536;
        float f1 = (1.0f - fyl) * ((1.0f - fxl) * lr1[jy0 * 256 + jx0] + fxl * lr1[jy0 * 256 + jx1])
                 + fyl * ((1.0f - fxl) * lr1[jy1 * 256 + jx0] + fxl * lr1[jy1 * 256 + jx1]);
        float f2 = (1.0f - fyl) * ((1.0f - fxl) * lr2[jy0 * 256 + jx0] + fxl * lr2[jy0 * 256 + jx1])
                 + fyl * ((1.0f - fxl) * lr2[jy1 * 256 + jx0] + fxl * lr2[jy1 * 256 + jx1]);

        Yo[px] = Yv;
        Uo[px] = tanh_fast(uacc) + f1;
        Vo[px] = tanh_fast(vacc) + f2;
    }

    size_t base = ((size_t)n * 3) * 1048576 + (size_t)y * 1024 + x0;
    *(float4*)(out + base)            = make_float4(Yo[0], Yo[1], Yo[2], Yo[3]);
    *(float4*)(out + base + 1048576)  = make_float4(Uo[0], Uo[1], Uo[2], Uo[3]);
    *(float4*)(out + base + 2097152)  = make_float4(Vo[0], Vo[1], Vo[2], Vo[3]);
}

extern "C" void kernel_launch(void* const* d_in, const int* in_sizes, int n_in,
                              void* d_out, int out_size, void* d_ws, size_t ws_size,
                              hipStream_t stream)
{
    const float* low  = (const float*)d_in[0];
    const float* full = (const float*)d_in[1];
    const float* w0 = (const float*)d_in[2];  const float* b0 = (const float*)d_in[3];
    const float* w1 = (const float*)d_in[4];  const float* b1 = (const float*)d_in[5];
    const float* w2 = (const float*)d_in[6];  const float* b2 = (const float*)d_in[7];
    const float* w3 = (const float*)d_in[8];  const float* b3 = (const float*)d_in[9];
    const float* wl0 = (const float*)d_in[10]; const float* bl0 = (const float*)d_in[11];
    const float* wl1 = (const float*)d_in[12];
    const float* wg1 = (const float*)d_in[13]; const float* bg1 = (const float*)d_in[14];
    const float* wg2 = (const float*)d_in[15]; const float* bg2 = (const float*)d_in[16];
    const float* wf1 = (const float*)d_in[17]; const float* bf1 = (const float*)d_in[18];
    const float* wf2 = (const float*)d_in[19]; const float* bf2 = (const float*)d_in[20];
    const float* wf3 = (const float*)d_in[21]; const float* bf3 = (const float*)d_in[22];
    const float* wlin = (const float*)d_in[23]; const float* blin = (const float*)d_in[24];
    const float* wgd1 = (const float*)d_in[25]; const float* bgd1 = (const float*)d_in[26];
    const float* wgd2 = (const float*)d_in[27]; const float* bgd2 = (const float*)d_in[28];
    const float* wau1 = (const float*)d_in[29]; const float* bau1 = (const float*)d_in[30];
    const float* wau2 = (const float*)d_in[31]; const float* bau2 = (const float*)d_in[32];
    const float* wav1 = (const float*)d_in[33]; const float* bav1 = (const float*)d_in[34];
    const float* wav2 = (const float*)d_in[35]; const float* bav2 = (const float*)d_in[36];
    float* out = (float*)d_out;

    float* ws = (float*)d_ws;
    float* t1b    = ws;
    float* splat  = t1b + 262144;
    float* l0o    = splat + 65536;
    float* localb = l0o + 65536;
    float* x1b    = localb + 65536;
    float* x2b    = x1b + 32768;
    float* avec   = x2b + 16384;
    float* gridb  = avec + 1792;

    k01_fused<<<64, 256, 0, stream>>>(low, w0, b0, w1, b1, t1b);
    k23_fused<<<64, 256, 0, stream>>>(t1b, w2, b2, w3, b3, splat);
    k5_l0_g1_means<<<6208, 256, 0, stream>>>(splat, wl0, bl0, l0o, wg1, bg1, x1b, avec);
    k6_l1_g2_means<<<5248, 256, 0, stream>>>(l0o, wl1, localb, x1b, wg2, bg2, x2b, avec);
    kfc_fuse<<<384, 256, 0, stream>>>(avec, x2b, wf1, bf1, wf2, bf2, wf3, bf3,
                                      localb, wlin, blin, gridb);
    hdr_out_v2<<<4096, 256, 0, stream>>>(full, low, gridb,
        wgd1, bgd1, wgd2, bgd2, wau1, bau1, wau2, bau2, wav1, bav1, wav2, bav2, out);
}

// Round 6
// 362.744 us; speedup vs baseline: 1.6559x; 1.6559x over previous
//
#include <hip/hip_runtime.h>
#include <math.h>

// ---------------------------------------------------------------------------
// HDRNet, N=4, low 256x256, full 1024x1024. 8-launch pipeline (R6):
//   conv0, conv1 (thread-per-output, unrolled), conv2, conv3 (split-K)
//   k5: l0 + g1 + splat-means | k6: l1 + g2 + x1-means
//   kfc: redundant-FC + fuse_grid | hdr: R2 kernel, plain launch_bounds(256)
// NOTE: __launch_bounds__(256,4) on hdr forced VGPR 64 -> ~420MB scratch
// spill (R5 regression). Keep plain (256): VGPR=128, 87us measured.
// Workspace floats: t0 524288 | t1 262144 | t2 131072 | splat 65536 |
// l0o 65536 | local 65536 | x1 32768 | x2 16384 | avec 1792 | grid 98304
// ---------------------------------------------------------------------------

__device__ __forceinline__ float tanh_fast(float x) {
    float e = __expf(2.0f * x);
    return 1.0f - 2.0f / (e + 1.0f);
}

// ---- small-Cin stride-2 conv, thread-per-output, fully unrolled ----
template<int CIN, int COUT, int HIN, int WIN, int HOUT, int WOUT>
__global__ __launch_bounds__(256) void conv_s2_small(
    const float* __restrict__ in, const float* __restrict__ w,
    const float* __restrict__ b, float* __restrict__ out)
{
    int idx = blockIdx.x * 256 + threadIdx.x;
    int wo = idx % WOUT; int t = idx / WOUT;
    int ho = t % HOUT; t /= HOUT;
    int co = t % COUT; int n = t / COUT;
    float acc = b[co];
    int hi0 = ho * 2 - 1, wi0 = wo * 2 - 1;
    const float* wp = w + (size_t)co * CIN * 9;
    #pragma unroll
    for (int ci = 0; ci < CIN; ++ci) {
        const float* ip = in + ((size_t)(n * CIN + ci)) * HIN * WIN;
        const float* wc = wp + ci * 9;
        #pragma unroll
        for (int kh = 0; kh < 3; ++kh) {
            int hi = hi0 + kh;
            if ((unsigned)hi >= (unsigned)HIN) continue;
            const float* row = ip + hi * WIN;
            #pragma unroll
            for (int kw = 0; kw < 3; ++kw) {
                int wi = wi0 + kw;
                if ((unsigned)wi >= (unsigned)WIN) continue;
                acc = fmaf(wc[kh * 3 + kw], row[wi], acc);
            }
        }
    }
    out[idx] = fmaxf(acc, 0.0f);
}

// ---- PARTS-way input-channel-split 3x3 conv ----
template<int CIN, int PARTS, int STRIDE, bool RELU, bool HASB,
         int COUT, int HIN, int WIN, int HOUT, int WOUT>
__device__ __forceinline__ void conv_p_dev(
    const float* __restrict__ in, const float* __restrict__ w,
    const float* __restrict__ b, float* __restrict__ out,
    int tb, float* red)
{
    constexpr int CPT = CIN / PARTS;
    constexpr int OPB = 256 / PARTS;
    int part = threadIdx.x / OPB;
    int oidx = threadIdx.x % OPB;
    int o = tb * OPB + oidx;
    int wo = o % WOUT; int t = o / WOUT;
    int ho = t % HOUT; t /= HOUT;
    int co = t % COUT; int n = t / COUT;
    int hi0 = ho * STRIDE - 1, wi0 = wo * STRIDE - 1;
    const float* wp = w + ((size_t)co * CIN + part * CPT) * 9;
    const float* ip = in + ((size_t)n * CIN + part * CPT) * HIN * WIN;
    float acc = 0.0f;
    #pragma unroll
    for (int ci = 0; ci < CPT; ++ci) {
        const float* ic = ip + (size_t)ci * HIN * WIN;
        const float* wc = wp + ci * 9;
        #pragma unroll
        for (int kh = 0; kh < 3; ++kh) {
            int hi = hi0 + kh;
            if ((unsigned)hi >= (unsigned)HIN) continue;
            const float* row = ic + hi * WIN;
            #pragma unroll
            for (int kw = 0; kw < 3; ++kw) {
                int wi = wi0 + kw;
                if ((unsigned)wi >= (unsigned)WIN) continue;
                acc = fmaf(wc[kh * 3 + kw], row[wi], acc);
            }
        }
    }
    red[threadIdx.x] = acc;
    __syncthreads();
    if (part == 0) {
        float s = acc;
        #pragma unroll
        for (int p = 1; p < PARTS; ++p) s += red[p * OPB + oidx];
        if (HASB) s += b[co];
        if (RELU) s = fmaxf(s, 0.0f);
        out[o] = s;
    }
}

// conv2: t1(4,16,64,64) -> t2(4,32,32,32)
__global__ __launch_bounds__(256) void conv2_k(
    const float* __restrict__ in, const float* __restrict__ w,
    const float* __restrict__ b, float* __restrict__ out)
{
    __shared__ float red[256];
    conv_p_dev<16, 4, 2, true, true, 32, 64, 64, 32, 32>(in, w, b, out, blockIdx.x, red);
}

// conv3: t2 -> splat(4,64,16,16)
__global__ __launch_bounds__(256) void conv3_k(
    const float* __restrict__ in, const float* __restrict__ w,
    const float* __restrict__ b, float* __restrict__ out)
{
    __shared__ float red[256];
    conv_p_dev<32, 8, 2, true, true, 64, 32, 32, 16, 16>(in, w, b, out, blockIdx.x, red);
}

// k5: l0 (4096 tbs) + g1 (2048 tbs) + splat-means (64 blocks)
__global__ __launch_bounds__(256) void k5_l0_g1_means(
    const float* __restrict__ splat,
    const float* __restrict__ wl0, const float* __restrict__ bl0, float* __restrict__ l0o,
    const float* __restrict__ wg1, const float* __restrict__ bg1, float* __restrict__ x1,
    float* __restrict__ avec)
{
    __shared__ float red[256];
    int bid = blockIdx.x;
    if (bid < 4096) {
        conv_p_dev<64, 16, 1, true, true, 64, 16, 16, 16, 16>(splat, wl0, bl0, l0o, bid, red);
    } else if (bid < 6144) {
        conv_p_dev<64, 16, 2, true, true, 128, 16, 16, 8, 8>(splat, wg1, bg1, x1, bid - 4096, red);
    } else {
        int wid = (bid - 6144) * 4 + (threadIdx.x >> 6);   // 0..255
        int lane = threadIdx.x & 63;
        int n = wid >> 6, c = wid & 63;
        const float* p = splat + ((size_t)(n * 64 + c)) * 256;
        float s = p[lane] + p[lane + 64] + p[lane + 128] + p[lane + 192];
        #pragma unroll
        for (int off = 32; off; off >>= 1) s += __shfl_down(s, off, 64);
        if (lane == 0) avec[n * 448 + c] = s * (1.0f / 256.0f);
    }
}

// k6: l1 (4096 tbs) + g2 (1024 tbs) + x1-means (128 blocks)
__global__ __launch_bounds__(256) void k6_l1_g2_means(
    const float* __restrict__ l0o, const float* __restrict__ wl1, float* __restrict__ localb,
    const float* __restrict__ x1, const float* __restrict__ wg2,
    const float* __restrict__ bg2, float* __restrict__ x2,
    float* __restrict__ avec)
{
    __shared__ float red[256];
    int bid = blockIdx.x;
    if (bid < 4096) {
        conv_p_dev<64, 16, 1, false, false, 64, 16, 16, 16, 16>(l0o, wl1, nullptr, localb, bid, red);
    } else if (bid < 5120) {
        conv_p_dev<128, 16, 2, true, true, 256, 8, 8, 4, 4>(x1, wg2, bg2, x2, bid - 4096, red);
    } else {
        int wid = (bid - 5120) * 4 + (threadIdx.x >> 6);   // 0..511
        int lane = threadIdx.x & 63;
        int n = wid >> 7, c = wid & 127;
        const float* p = x1 + ((size_t)(n * 128 + c)) * 64;
        float s = p[lane];
        #pragma unroll
        for (int off = 32; off; off >>= 1) s += __shfl_down(s, off, 64);
        if (lane == 0) avec[n * 448 + 64 + c] = s * (1.0f / 64.0f);
    }
}

// kfc: per-block redundant FC chain (448->256->128->64 in LDS) + fuse_grid.
__global__ __launch_bounds__(256) void kfc_fuse(
    const float* __restrict__ avec, const float* __restrict__ x2,
    const float* __restrict__ wf1, const float* __restrict__ bf1,
    const float* __restrict__ wf2, const float* __restrict__ bf2,
    const float* __restrict__ wf3, const float* __restrict__ bf3,
    const float* __restrict__ local,
    const float* __restrict__ wlin, const float* __restrict__ blin,
    float* __restrict__ grid)
{
    __shared__ float a[448];
    __shared__ float h1[256];
    __shared__ float h2[128];
    __shared__ float gl[64];
    int n = blockIdx.x / 96; int k = blockIdx.x % 96; int t = threadIdx.x;
    if (t < 192) a[t] = avec[n * 448 + t];
    {
        const float* p = x2 + ((size_t)(n * 256 + t)) * 16;
        float s = 0.0f;
        #pragma unroll
        for (int i = 0; i < 16; ++i) s += p[i];
        a[192 + t] = s * (1.0f / 16.0f);
    }
    __syncthreads();
    {
        float a0 = 0, a1 = 0, a2 = 0, a3 = 0;
        const float* wp = wf1 + (size_t)t * 448;
        for (int i = 0; i < 448; i += 4) {
            a0 = fmaf(wp[i], a[i], a0); a1 = fmaf(wp[i + 1], a[i + 1], a1);
            a2 = fmaf(wp[i + 2], a[i + 2], a2); a3 = fmaf(wp[i + 3], a[i + 3], a3);
        }
        h1[t] = fmaxf(a0 + a1 + a2 + a3 + bf1[t], 0.0f);
    }
    __syncthreads();
    if (t < 128) {
        float a0 = 0, a1 = 0, a2 = 0, a3 = 0;
        const float* wp = wf2 + (size_t)t * 256;
        for (int i = 0; i < 256; i += 4) {
            a0 = fmaf(wp[i], h1[i], a0); a1 = fmaf(wp[i + 1], h1[i + 1], a1);
            a2 = fmaf(wp[i + 2], h1[i + 2], a2); a3 = fmaf(wp[i + 3], h1[i + 3], a3);
        }
        h2[t] = fmaxf(a0 + a1 + a2 + a3 + bf2[t], 0.0f);
    }
    __syncthreads();
    if (t < 64) {
        float a0 = 0, a1 = 0, a2 = 0, a3 = 0;
        const float* wp = wf3 + (size_t)t * 128;
        for (int i = 0; i < 128; i += 4) {
            a0 = fmaf(wp[i], h2[i], a0); a1 = fmaf(wp[i + 1], h2[i + 1], a1);
            a2 = fmaf(wp[i + 2], h2[i + 2], a2); a3 = fmaf(wp[i + 3], h2[i + 3], a3);
        }
        gl[t] = fmaxf(a0 + a1 + a2 + a3 + bf3[t], 0.0f);
    }
    __syncthreads();
    float acc = blin[k];
    const float* wp = wlin + k * 64;
    const float* lo = local + (size_t)n * 64 * 256 + t;
    #pragma unroll 8
    for (int c = 0; c < 64; ++c)
        acc = fmaf(wp[c], fmaxf(gl[c] + lo[c * 256], 0.0f), acc);
    int ch = k >> 3; int z = k & 7;
    grid[(((size_t)(n * 8 + z)) * 256 + t) * 12 + ch] = acc;
}

// ---- hdr: R2 kernel verbatim. PLAIN launch_bounds(256): VGPR=128, 87us.
__global__ __launch_bounds__(256) void hdr_out_v2(
    const float* __restrict__ full, const float* __restrict__ low,
    const float* __restrict__ grid,
    const float* __restrict__ wgd1, const float* __restrict__ bgd1,
    const float* __restrict__ wgd2, const float* __restrict__ bgd2,
    const float* __restrict__ wau1, const float* __restrict__ bau1,
    const float* __restrict__ wau2, const float* __restrict__ bau2,
    const float* __restrict__ wav1, const float* __restrict__ bav1,
    const float* __restrict__ wav2, const float* __restrict__ bav2,
    float* __restrict__ out)
{
    int tid = blockIdx.x * 256 + threadIdx.x;
    int x0 = (tid & 255) << 2;
    int y = (tid >> 8) & 1023;
    int n = tid >> 18;
    const float* fp = full + ((size_t)n << 20);

    float v[3][6];
    #pragma unroll
    for (int r = 0; r < 3; ++r) {
        int yy = y + r - 1;
        bool okr = (unsigned)yy < 1024u;
        const float* row = fp + (size_t)yy * 1024;
        if (okr) {
            float4 m = *(const float4*)(row + x0);
            v[r][1] = m.x; v[r][2] = m.y; v[r][3] = m.z; v[r][4] = m.w;
            v[r][0] = (x0 > 0) ? row[x0 - 1] : 0.0f;
            v[r][5] = (x0 < 1020) ? row[x0 + 4] : 0.0f;
        } else {
            #pragma unroll
            for (int j = 0; j < 6; ++j) v[r][j] = 0.0f;
        }
    }

    float gacc[4];
    float bb = bgd2[0];
    #pragma unroll
    for (int px = 0; px < 4; ++px) gacc[px] = bb;
    #pragma unroll
    for (int k = 0; k < 16; ++k) {
        const float* wk = wgd1 + k * 9;
        float q0 = wk[0], q1 = wk[1], q2 = wk[2];
        float q3 = wk[3], q4 = wk[4], q5 = wk[5];
        float q6 = wk[6], q7 = wk[7], q8 = wk[8];
        float bk = bgd1[k], wo = wgd2[k];
        #pragma unroll
        for (int px = 0; px < 4; ++px) {
            float h = bk;
            h = fmaf(q0, v[0][px], h); h = fmaf(q1, v[0][px + 1], h); h = fmaf(q2, v[0][px + 2], h);
            h = fmaf(q3, v[1][px], h); h = fmaf(q4, v[1][px + 1], h); h = fmaf(q5, v[1][px + 2], h);
            h = fmaf(q6, v[2][px], h); h = fmaf(q7, v[2][px + 1], h); h = fmaf(q8, v[2][px + 2], h);
            gacc[px] = fmaf(wo, fmaxf(h, 0.0f), gacc[px]);
        }
    }

    const float* gbase = grid + (size_t)n * 24576;
    float Yo[4], Uo[4], Vo[4];

    #pragma unroll
    for (int px = 0; px < 4; ++px) {
        int x = x0 + px;
        float g = tanh_fast(gacc[px]);

        float gxc = (x * (32.0f / 1023.0f) - 1.0f) * 0.5f;
        float gyc = (y * (32.0f / 1023.0f) - 1.0f) * 0.5f;
        float gzc = 4.0f * g + 3.5f;
        float x0f = floorf(gxc), y0f = floorf(gyc), z0f = floorf(gzc);
        float fx = gxc - x0f, fy = gyc - y0f, fz = gzc - z0f;
        int ix = (int)x0f, iy = (int)y0f, iz = (int)z0f;

        float wx0 = (ix >= 0 && ix < 16) ? (1.0f - fx) : 0.0f;
        float wx1 = (ix + 1 < 16) ? fx : 0.0f;
        float wy0 = (iy >= 0 && iy < 16) ? (1.0f - fy) : 0.0f;
        float wy1 = (iy + 1 < 16) ? fy : 0.0f;
        float wz0 = (iz >= 0 && iz < 8) ? (1.0f - fz) : 0.0f;
        float wz1 = (iz + 1 >= 0 && iz + 1 < 8) ? fz : 0.0f;
        int xi0 = min(max(ix, 0), 15), xi1 = min(ix + 1, 15);
        int yi0 = min(max(iy, 0), 15), yi1 = min(iy + 1, 15);
        int zi0 = min(max(iz, 0), 7),  zi1 = min(max(iz + 1, 0), 7);

        float w00 = wy0 * wx0, w01 = wy0 * wx1, w10 = wy1 * wx0, w11 = wy1 * wx1;
        int o00 = yi0 * 16 + xi0, o01 = yi0 * 16 + xi1;
        int o10 = yi1 * 16 + xi0, o11 = yi1 * 16 + xi1;
        int z0b = zi0 * 256, z1b = zi1 * 256;

        float acc[12];
        #pragma unroll
        for (int i = 0; i < 12; ++i) acc[i] = 0.0f;

        #define CORNER(OFF, WK) { \
            const float4* q = (const float4*)(gbase + (size_t)(OFF) * 12); \
            float wk_ = (WK); \
            float4 A = q[0], B = q[1], C = q[2]; \
            acc[0] = fmaf(wk_, A.x, acc[0]); acc[1] = fmaf(wk_, A.y, acc[1]); \
            acc[2] = fmaf(wk_, A.z, acc[2]); acc[3] = fmaf(wk_, A.w, acc[3]); \
            acc[4] = fmaf(wk_, B.x, acc[4]); acc[5] = fmaf(wk_, B.y, acc[5]); \
            acc[6] = fmaf(wk_, B.z, acc[6]); acc[7] = fmaf(wk_, B.w, acc[7]); \
            acc[8] = fmaf(wk_, C.x, acc[8]); acc[9] = fmaf(wk_, C.y, acc[9]); \
            acc[10] = fmaf(wk_, C.z, acc[10]); acc[11] = fmaf(wk_, C.w, acc[11]); }

        CORNER(z0b + o00, wz0 * w00)
        CORNER(z0b + o01, wz0 * w01)
        CORNER(z0b + o10, wz0 * w10)
        CORNER(z0b + o11, wz0 * w11)
        CORNER(z1b + o00, wz1 * w00)
        CORNER(z1b + o01, wz1 * w01)
        CORNER(z1b + o10, wz1 * w10)
        CORNER(z1b + o11, wz1 * w11)
        #undef CORNER

        float p = v[1][px + 1];
        float Yv = fmaf(p, acc[3],  acc[0] + acc[1] + acc[2]);
        float U0 = fmaf(p, acc[7],  acc[4] + acc[5] + acc[6]);
        float V0 = fmaf(p, acc[11], acc[8] + acc[9] + acc[10]);

        float uacc = bau2[0];
        #pragma unroll
        for (int k = 0; k < 16; ++k)
            uacc = fmaf(wau2[k], fmaxf(fmaf(wau1[k], U0, bau1[k]), 0.0f), uacc);
        float vacc = bav2[0];
        #pragma unroll
        for (int k = 0; k < 16; ++k)
            vacc = fmaf(wav2[k], fmaxf(fmaf(wav1[k], V0, bav1[k]), 0.0f), vacc);

        float sx = (x + 0.5f) * 0.25f - 0.5f;
        float sy = (y + 0.5f) * 0.25f - 0.5f;
        float sxf = floorf(sx), syf = floorf(sy);
        float fxl = sx - sxf, fyl = sy - syf;
        int jx0 = max((int)sxf, 0), jx1 = min((int)sxf + 1, 255);
        int jy0 = max((int)syf, 0), jy1 = min((int)syf + 1, 255);
        const float* lr1 = low + ((size_t)(n * 3 + 1)) * 65536;
        const float* lr2 = low + ((size_t)(n * 3 + 2)) * 65536;
        float f1 = (1.0f - fyl) * ((1.0f - fxl) * lr1[jy0 * 256 + jx0] + fxl * lr1[jy0 * 256 + jx1])
                 + fyl * ((1.0f - fxl) * lr1[jy1 * 256 + jx0] + fxl * lr1[jy1 * 256 + jx1]);
        float f2 = (1.0f - fyl) * ((1.0f - fxl) * lr2[jy0 * 256 + jx0] + fxl * lr2[jy0 * 256 + jx1])
                 + fyl * ((1.0f - fxl) * lr2[jy1 * 256 + jx0] + fxl * lr2[jy1 * 256 + jx1]);

        Yo[px] = Yv;
        Uo[px] = tanh_fast(uacc) + f1;
        Vo[px] = tanh_fast(vacc) + f2;
    }

    size_t base = ((size_t)n * 3) * 1048576 + (size_t)y * 1024 + x0;
    *(float4*)(out + base)            = make_float4(Yo[0], Yo[1], Yo[2], Yo[3]);
    *(float4*)(out + base + 1048576)  = make_float4(Uo[0], Uo[1], Uo[2], Uo[3]);
    *(float4*)(out + base + 2097152)  = make_float4(Vo[0], Vo[1], Vo[2], Vo[3]);
}

extern "C" void kernel_launch(void* const* d_in, const int* in_sizes, int n_in,
                              void* d_out, int out_size, void* d_ws, size_t ws_size,
                              hipStream_t stream)
{
    const float* low  = (const float*)d_in[0];
    const float* full = (const float*)d_in[1];
    const float* w0 = (const float*)d_in[2];  const float* b0 = (const float*)d_in[3];
    const float* w1 = (const float*)d_in[4];  const float* b1 = (const float*)d_in[5];
    const float* w2 = (const float*)d_in[6];  const float* b2 = (const float*)d_in[7];
    const float* w3 = (const float*)d_in[8];  const float* b3 = (const float*)d_in[9];
    const float* wl0 = (const float*)d_in[10]; const float* bl0 = (const float*)d_in[11];
    const float* wl1 = (const float*)d_in[12];
    const float* wg1 = (const float*)d_in[13]; const float* bg1 = (const float*)d_in[14];
    const float* wg2 = (const float*)d_in[15]; const float* bg2 = (const float*)d_in[16];
    const float* wf1 = (const float*)d_in[17]; const float* bf1 = (const float*)d_in[18];
    const float* wf2 = (const float*)d_in[19]; const float* bf2 = (const float*)d_in[20];
    const float* wf3 = (const float*)d_in[21]; const float* bf3 = (const float*)d_in[22];
    const float* wlin = (const float*)d_in[23]; const float* blin = (const float*)d_in[24];
    const float* wgd1 = (const float*)d_in[25]; const float* bgd1 = (const float*)d_in[26];
    const float* wgd2 = (const float*)d_in[27]; const float* bgd2 = (const float*)d_in[28];
    const float* wau1 = (const float*)d_in[29]; const float* bau1 = (const float*)d_in[30];
    const float* wau2 = (const float*)d_in[31]; const float* bau2 = (const float*)d_in[32];
    const float* wav1 = (const float*)d_in[33]; const float* bav1 = (const float*)d_in[34];
    const float* wav2 = (const float*)d_in[35]; const float* bav2 = (const float*)d_in[36];
    float* out = (float*)d_out;

    float* ws = (float*)d_ws;
    float* t0b    = ws;
    float* t1b    = t0b + 524288;
    float* t2b    = t1b + 262144;
    float* splat  = t2b + 131072;
    float* l0o    = splat + 65536;
    float* localb = l0o + 65536;
    float* x1b    = localb + 65536;
    float* x2b    = x1b + 32768;
    float* avec   = x2b + 16384;
    float* gridb  = avec + 1792;

    conv_s2_small<3, 8, 256, 256, 128, 128><<<2048, 256, 0, stream>>>(low, w0, b0, t0b);
    conv_s2_small<8, 16, 128, 128, 64, 64><<<1024, 256, 0, stream>>>(t0b, w1, b1, t1b);
    conv2_k<<<2048, 256, 0, stream>>>(t1b, w2, b2, t2b);
    conv3_k<<<2048, 256, 0, stream>>>(t2b, w3, b3, splat);
    k5_l0_g1_means<<<6208, 256, 0, stream>>>(splat, wl0, bl0, l0o, wg1, bg1, x1b, avec);
    k6_l1_g2_means<<<5248, 256, 0, stream>>>(l0o, wl1, localb, x1b, wg2, bg2, x2b, avec);
    kfc_fuse<<<384, 256, 0, stream>>>(avec, x2b, wf1, bf1, wf2, bf2, wf3, bf3,
                                      localb, wlin, blin, gridb);
    hdr_out_v2<<<4096, 256, 0, stream>>>(full, low, gridb,
        wgd1, bgd1, wgd2, bgd2, wau1, bau1, wau2, bau2, wav1, bav1, wav2, bav2, out);
}